// Round 7
// baseline (500.040 us; speedup 1.0000x reference)
//
#include <hip/hip_runtime.h>
#include <hip/hip_bf16.h>

typedef unsigned short u16;
typedef unsigned int u32;
typedef __bf16 v8bf __attribute__((ext_vector_type(8)));
typedef float v4f __attribute__((ext_vector_type(4)));

#define B_SZ 8
#define S_LEN 1024
#define IN_DIM 256
#define DMODEL 512
#define NHEAD 8
#define DK 64
#define FF_DIM 2048
#define MROWS (B_SZ * S_LEN)   // 8192
#define QSCALE 0.1803368801111204f   // 0.125 * log2(e)

__device__ __forceinline__ u16 f2bf(float f) {
    unsigned int x = __float_as_uint(f);
    unsigned int r = (x + 0x7fffu + ((x >> 16) & 1u)) >> 16;
    return (u16)r;
}

// async global->LDS DMA, 16B per lane; lds dest is wave-uniform base + lane*16
__device__ __forceinline__ void gl16(const u16* g, u16* l) {
    __builtin_amdgcn_global_load_lds((const __attribute__((address_space(1))) unsigned int*)g,
                                     (__attribute__((address_space(3))) unsigned int*)l, 16, 0, 0);
}

// ---------------- elementwise f32 -> bf16 (inputs matrix) ----------------
__global__ __launch_bounds__(256) void conv_bf16_kernel(const float* __restrict__ in,
                                                        u16* __restrict__ out, int n4) {
    int i = blockIdx.x * 256 + threadIdx.x;
    if (i < n4) {
        float4 v = ((const float4*)in)[i];
        ushort4 o;
        o.x = f2bf(v.x); o.y = f2bf(v.y); o.z = f2bf(v.z); o.w = f2bf(v.w);
        ((ushort4*)out)[i] = o;
    }
}

// ------------- batched transpose+convert: (K,N) f32 -> (N,K) bf16 -------------
struct TDesc { const float* src; u16* dst; int K; int N; };
struct TArgs { TDesc d[13]; };

__global__ void transpose_conv_kernel(TArgs args) {
    TDesc t = args.d[blockIdx.z];
    int k0 = blockIdx.x * 32, n0 = blockIdx.y * 32;
    if (k0 >= t.K || n0 >= t.N) return;
    __shared__ float tile[32][33];
    int tx = threadIdx.x, ty = threadIdx.y;
#pragma unroll
    for (int j = 0; j < 4; j++) {
        int k = k0 + ty + j * 8;
        tile[ty + j * 8][tx] = t.src[(size_t)k * t.N + n0 + tx];
    }
    __syncthreads();
#pragma unroll
    for (int j = 0; j < 4; j++) {
        int n = n0 + ty + j * 8;
        t.dst[(size_t)n * t.K + k0 + tx] = f2bf(tile[tx][ty + j * 8]);
    }
}

// ---------------- LayerNorm: fp32 in -> bf16 (or fp32) out ----------------
template <bool OUT_BF16>
__global__ __launch_bounds__(256) void ln_kernel(const float* __restrict__ x,
                                                 const float* __restrict__ g,
                                                 const float* __restrict__ b,
                                                 void* __restrict__ out) {
    int row = blockIdx.x * 4 + (threadIdx.x >> 6);
    int lane = threadIdx.x & 63;
    const float4* xr = (const float4*)(x + (size_t)row * DMODEL);
    float4 v0 = xr[lane], v1 = xr[lane + 64];
    float s = v0.x + v0.y + v0.z + v0.w + v1.x + v1.y + v1.z + v1.w;
    float sq = v0.x * v0.x + v0.y * v0.y + v0.z * v0.z + v0.w * v0.w +
               v1.x * v1.x + v1.y * v1.y + v1.z * v1.z + v1.w * v1.w;
#pragma unroll
    for (int m = 1; m < 64; m <<= 1) {
        s += __shfl_xor(s, m);
        sq += __shfl_xor(sq, m);
    }
    float mean = s * (1.0f / DMODEL);
    float var = sq * (1.0f / DMODEL) - mean * mean;
    float rstd = rsqrtf(var + 1e-5f);
    const float4* g4 = (const float4*)g;
    const float4* b4 = (const float4*)b;
    float4 ga = g4[lane], gb = g4[lane + 64], ba = b4[lane], bb = b4[lane + 64];
    float4 r0, r1;
    r0.x = (v0.x - mean) * rstd * ga.x + ba.x;
    r0.y = (v0.y - mean) * rstd * ga.y + ba.y;
    r0.z = (v0.z - mean) * rstd * ga.z + ba.z;
    r0.w = (v0.w - mean) * rstd * ga.w + ba.w;
    r1.x = (v1.x - mean) * rstd * gb.x + bb.x;
    r1.y = (v1.y - mean) * rstd * gb.y + bb.y;
    r1.z = (v1.z - mean) * rstd * gb.z + bb.z;
    r1.w = (v1.w - mean) * rstd * gb.w + bb.w;
    if (OUT_BF16) {
        ushort4 o0, o1;
        o0.x = f2bf(r0.x); o0.y = f2bf(r0.y); o0.z = f2bf(r0.z); o0.w = f2bf(r0.w);
        o1.x = f2bf(r1.x); o1.y = f2bf(r1.y); o1.z = f2bf(r1.z); o1.w = f2bf(r1.w);
        ((ushort4*)out)[(size_t)row * 128 + lane] = o0;
        ((ushort4*)out)[(size_t)row * 128 + 64 + lane] = o1;
    } else {
        ((float4*)out)[(size_t)row * 128 + lane] = r0;
        ((float4*)out)[(size_t)row * 128 + 64 + lane] = r1;
    }
}

// ------- shared GEMM core: (MT*32) x (NT*32) tile, BK=64, XOR-swizzled LDS -------
// global_load_lds width-16; swizzle permutes each lane's GLOBAL source col-block so
// LDS[row][cs] = G[row][cs ^ (row&7)] -> conflict-free b128 frag reads, no padding.
template <int MT, int NT>
__device__ __forceinline__ void gemm_core(const u16* __restrict__ A, const u16* __restrict__ Bt,
                                          int K, v4f (&acc)[MT][NT]) {
    constexpr int BM = MT * 32;
    constexpr int BN = NT * 32;
    __shared__ u16 As[BM * 64];
    __shared__ u16 Bs[BN * 64];
    int tid = threadIdx.x;
    int n0 = blockIdx.x * BN, m0 = blockIdx.y * BM;
    int w = tid >> 6, lane = tid & 63;
    int wr = (w >> 1) * (BM / 2), wc = (w & 1) * (BN / 2);
    int lr = lane & 15, lq = lane >> 4;
    int r8 = lane >> 3, cb = lane & 7;
    int scol = (cb ^ r8) * 8;

    v4f zero = {0.f, 0.f, 0.f, 0.f};
#pragma unroll
    for (int i = 0; i < MT; i++)
#pragma unroll
        for (int j = 0; j < NT; j++) acc[i][j] = zero;

    const u16* gA[MT]; u16* lA[MT];
#pragma unroll
    for (int j = 0; j < MT; j++) {
        int row0 = (MT * 8) * w + j * 8;
        gA[j] = A + (size_t)(m0 + row0 + r8) * K + scol;
        lA[j] = As + row0 * 64;
    }
    const u16* gB[NT]; u16* lB[NT];
#pragma unroll
    for (int j = 0; j < NT; j++) {
        int row0 = (NT * 8) * w + j * 8;
        gB[j] = Bt + (size_t)(n0 + row0 + r8) * K + scol;
        lB[j] = Bs + row0 * 64;
    }

    for (int k0 = 0; k0 < K; k0 += 64) {
#pragma unroll
        for (int j = 0; j < MT; j++) gl16(gA[j], lA[j]);
#pragma unroll
        for (int j = 0; j < NT; j++) gl16(gB[j], lB[j]);
        __syncthreads();   // vmcnt drain -> tiles ready
#pragma unroll
        for (int kk = 0; kk < 2; kk++) {
            int xb = ((kk * 4 + lq) ^ (lr & 7)) * 8;
            v8bf af[MT], bfr[NT];
#pragma unroll
            for (int i = 0; i < MT; i++)
                af[i] = *(const v8bf*)&As[(wr + i * 16 + lr) * 64 + xb];
#pragma unroll
            for (int j = 0; j < NT; j++)
                bfr[j] = *(const v8bf*)&Bs[(wc + j * 16 + lr) * 64 + xb];
#pragma unroll
            for (int mt = 0; mt < MT; mt++)
#pragma unroll
                for (int nt = 0; nt < NT; nt++)
                    acc[mt][nt] = __builtin_amdgcn_mfma_f32_16x16x32_bf16(af[mt], bfr[nt], acc[mt][nt], 0, 0, 0);
        }
        __syncthreads();   // frag reads done before next DMA overwrites
#pragma unroll
        for (int j = 0; j < MT; j++) gA[j] += 64;
#pragma unroll
        for (int j = 0; j < NT; j++) gB[j] += 64;
    }
}

// ---- input projection: fp32 out + bias + sinusoid PE (N=512, 128x64) ----
__global__ __launch_bounds__(256) void gemm_in_kernel(const u16* __restrict__ A,
                                                      const u16* __restrict__ Bt,
                                                      const float* __restrict__ bias,
                                                      float* __restrict__ Out, int K) {
    v4f acc[4][2];
    gemm_core<4, 2>(A, Bt, K, acc);
    int tid = threadIdx.x, w = tid >> 6, lane = tid & 63;
    int lr = lane & 15, lq = lane >> 4;
    int wr = (w >> 1) * 64, wc = (w & 1) * 32;
    int n0 = blockIdx.x * 64, m0 = blockIdx.y * 128;
#pragma unroll
    for (int mt = 0; mt < 4; mt++) {
#pragma unroll
        for (int nt = 0; nt < 2; nt++) {
            int col = n0 + wc + nt * 16 + lr;
            float bcol = bias[col];
            float freq = __builtin_amdgcn_exp2f((float)(col & ~1) * (-0.025953277f));
#pragma unroll
            for (int reg = 0; reg < 4; reg++) {
                int row = m0 + wr + mt * 16 + lq * 4 + reg;
                float rev = (float)(row & (S_LEN - 1)) * freq * 0.15915494309189535f;
                float fr = __builtin_amdgcn_fractf(rev);
                float pe = (col & 1) ? __builtin_amdgcn_cosf(fr) : __builtin_amdgcn_sinf(fr);
                Out[(size_t)row * DMODEL + col] = acc[mt][nt][reg] + bcol + pe;
            }
        }
    }
}

// ---- fused QKV projection: N=1536 (128x128); segment block-uniform ----
__global__ __launch_bounds__(256) void gemm_qkv_kernel(const u16* __restrict__ A,
                                                       const u16* __restrict__ Bt,
                                                       const float* __restrict__ bq,
                                                       const float* __restrict__ bk,
                                                       const float* __restrict__ bv,
                                                       u16* __restrict__ Qo,
                                                       u16* __restrict__ Ko,
                                                       u16* __restrict__ Vto, int K) {
    v4f acc[4][4];
    gemm_core<4, 4>(A, Bt, K, acc);
    int tid = threadIdx.x, w = tid >> 6, lane = tid & 63;
    int lr = lane & 15, lq = lane >> 4;
    int wr = (w >> 1) * 64, wc = (w & 1) * 64;
    int n0 = blockIdx.x * 128, m0 = blockIdx.y * 128;
    int seg = n0 >> 9;
#pragma unroll
    for (int mt = 0; mt < 4; mt++) {
#pragma unroll
        for (int nt = 0; nt < 4; nt++) {
            int col = (n0 + wc + nt * 16 + lr) & (DMODEL - 1);
            if (seg == 0) {
                float bcol = bq[col];
#pragma unroll
                for (int reg = 0; reg < 4; reg++) {
                    int row = m0 + wr + mt * 16 + lq * 4 + reg;
                    Qo[(size_t)row * DMODEL + col] = f2bf((acc[mt][nt][reg] + bcol) * QSCALE);
                }
            } else if (seg == 1) {
                float bcol = bk[col];
#pragma unroll
                for (int reg = 0; reg < 4; reg++) {
                    int row = m0 + wr + mt * 16 + lq * 4 + reg;
                    Ko[(size_t)row * DMODEL + col] = f2bf(acc[mt][nt][reg] + bcol);
                }
            } else {
                float bcol = bv[col];
                int row0 = m0 + wr + mt * 16 + lq * 4;
                int bb = row0 >> 10, s0 = row0 & (S_LEN - 1);
                ushort4 o;
                o.x = f2bf(acc[mt][nt][0] + bcol);
                o.y = f2bf(acc[mt][nt][1] + bcol);
                o.z = f2bf(acc[mt][nt][2] + bcol);
                o.w = f2bf(acc[mt][nt][3] + bcol);
                *(ushort4*)(Vto + ((size_t)(bb * DMODEL + col)) * S_LEN + s0) = o;
            }
        }
    }
}

// ---- FFN1: bf16 out + bias + ReLU (N=2048, 256x128 tile) ----
__global__ __launch_bounds__(256) void gemm_relu_kernel(const u16* __restrict__ A,
                                                        const u16* __restrict__ Bt,
                                                        const float* __restrict__ bias,
                                                        u16* __restrict__ Out, int N, int K) {
    v4f acc[8][4];
    gemm_core<8, 4>(A, Bt, K, acc);
    int tid = threadIdx.x, w = tid >> 6, lane = tid & 63;
    int lr = lane & 15, lq = lane >> 4;
    int wr = (w >> 1) * 128, wc = (w & 1) * 64;
    int n0 = blockIdx.x * 128, m0 = blockIdx.y * 256;
#pragma unroll
    for (int mt = 0; mt < 8; mt++) {
#pragma unroll
        for (int nt = 0; nt < 4; nt++) {
            int col = n0 + wc + nt * 16 + lr;
            float bcol = bias[col];
#pragma unroll
            for (int reg = 0; reg < 4; reg++) {
                int row = m0 + wr + mt * 16 + lq * 4 + reg;
                Out[(size_t)row * N + col] = f2bf(fmaxf(acc[mt][nt][reg] + bcol, 0.0f));
            }
        }
    }
}

// ---- O-proj / FFN2: fp32 out + bias + residual in-place (N=512, 128x64) ----
__global__ __launch_bounds__(256) void gemm_res_kernel(const u16* __restrict__ A,
                                                       const u16* __restrict__ Bt,
                                                       const float* __restrict__ bias,
                                                       float* __restrict__ Out, int K) {
    v4f acc[4][2];
    gemm_core<4, 2>(A, Bt, K, acc);
    int tid = threadIdx.x, w = tid >> 6, lane = tid & 63;
    int lr = lane & 15, lq = lane >> 4;
    int wr = (w >> 1) * 64, wc = (w & 1) * 32;
    int n0 = blockIdx.x * 64, m0 = blockIdx.y * 128;
#pragma unroll
    for (int mt = 0; mt < 4; mt++) {
#pragma unroll
        for (int nt = 0; nt < 2; nt++) {
            int col = n0 + wc + nt * 16 + lr;
            float bcol = bias[col];
#pragma unroll
            for (int reg = 0; reg < 4; reg++) {
                int row = m0 + wr + mt * 16 + lq * 4 + reg;
                size_t idx = (size_t)row * DMODEL + col;
                Out[idx] = Out[idx] + acc[mt][nt][reg] + bcol;
            }
        }
    }
}

// ---------------- MFMA flash attention v5 ----------------
// S^T operand-swap (A=K, B=Q); fixed softmax max; DMA-staged K/V (XOR swizzle);
// raw v_exp + truncating bf16 pack in the score epilogue.
#define LDP 68
__global__ __launch_bounds__(256) void fattn_kernel(const u16* __restrict__ Qg,
                                                    const u16* __restrict__ Kg,
                                                    const u16* __restrict__ Vtg,
                                                    const float* __restrict__ rb,
                                                    const int* __restrict__ lengths,
                                                    u16* __restrict__ O) {
    int qt = blockIdx.x, h = blockIdx.y, b = blockIdx.z;
    int tid = threadIdx.x, w = tid >> 6, lane = tid & 63;
    int lr = lane & 15, lq = lane >> 4;
    __shared__ u16 Ks[64 * 64];
    __shared__ u16 Vs[64 * 64];
    __shared__ u16 Pw[4][32 * LDP];
    __shared__ float rbs[128];
    int len = lengths[b];
    if (tid < 127) rbs[tid] = rb[h * 127 + tid] * 1.4426950408889634f;  // fold log2(e)

    int qw = qt * 128 + w * 32;   // wave's 32 q rows
    v8bf qa[2][2];                // B-operand: rows q = qw + ntq*16 + lr
#pragma unroll
    for (int ntq = 0; ntq < 2; ntq++) {
        size_t qrow = ((size_t)(b * S_LEN + qw + ntq * 16 + lr)) * DMODEL + h * DK;
        qa[ntq][0] = *(const v8bf*)(Qg + qrow + lq * 8);
        qa[ntq][1] = *(const v8bf*)(Qg + qrow + 32 + lq * 8);
    }

    v4f zero = {0.f, 0.f, 0.f, 0.f};
    v4f Oacc[2][4];
#pragma unroll
    for (int mt = 0; mt < 2; mt++)
#pragma unroll
        for (int nt = 0; nt < 4; nt++) Oacc[mt][nt] = zero;
    float lsum[2] = {0.f, 0.f};

    const u16* Kbase = Kg + ((size_t)b * S_LEN) * DMODEL + h * DK;
    const u16* Vbase = Vtg + ((size_t)(b * DMODEL + h * DK)) * S_LEN;
    u16* P = Pw[w];
    int r8 = lane >> 3, cb = lane & 7;
    int swz = (cb ^ r8) * 8;

    for (int kb0 = 0; kb0 < len; kb0 += 64) {
        __syncthreads();   // prev-iter LDS reads done (covers rbs on iter 0)
#pragma unroll
        for (int j = 0; j < 2; j++) {
            int row0 = w * 16 + j * 8;
            gl16(Kbase + (size_t)(kb0 + row0 + r8) * DMODEL + swz, Ks + row0 * 64);
            gl16(Vbase + (size_t)(row0 + r8) * S_LEN + kb0 + swz, Vs + row0 * 64);
        }
        __syncthreads();   // vmcnt drain -> Ks/Vs ready

        // A-operand K fragments (swizzled cols): key rows, d cols
        v8bf kf[4][2];
#pragma unroll
        for (int mtk = 0; mtk < 4; mtk++) {
#pragma unroll
            for (int half = 0; half < 2; half++) {
                int xb = ((half * 4 + lq) ^ (lr & 7)) * 8;
                kf[mtk][half] = *(const v8bf*)&Ks[(mtk * 16 + lr) * 64 + xb];
            }
        }

        // S^T = K @ Q^T : lane holds key = kb0+mtk*16+lq*4+r, q = qw+ntq*16+lr
        v4f S[4][2];
#pragma unroll
        for (int mtk = 0; mtk < 4; mtk++)
#pragma unroll
            for (int ntq = 0; ntq < 2; ntq++) {
                v4f s = __builtin_amdgcn_mfma_f32_16x16x32_bf16(kf[mtk][0], qa[ntq][0], zero, 0, 0, 0);
                S[mtk][ntq] = __builtin_amdgcn_mfma_f32_16x16x32_bf16(kf[mtk][1], qa[ntq][1], s, 0, 0, 0);
            }

        bool edge = (kb0 + 64 > len);
        int dmin = qw - (kb0 + 63), dmax = qw + 31 - kb0;
        bool perel = !(dmax <= -63 || dmin >= 63);
        float bconst = (dmax <= -63) ? rbs[0] : rbs[126];
#pragma unroll
        for (int mtk = 0; mtk < 4; mtk++) {
#pragma unroll
            for (int ntq = 0; ntq < 2; ntq++) {
                int q = qw + ntq * 16 + lr;
                float p[4];
#pragma unroll
                for (int r = 0; r < 4; r++) {
                    int key = kb0 + mtk * 16 + lq * 4 + r;
                    float s = S[mtk][ntq][r];
                    if (perel) {
                        int d = q - key;
                        d = d < -63 ? -63 : (d > 63 ? 63 : d);
                        s += rbs[d + 63];
                    } else {
                        s += bconst;
                    }
                    float pv = __builtin_amdgcn_exp2f(s);
                    if (edge && key >= len) pv = 0.f;
                    lsum[ntq] += pv;
                    p[r] = pv;
                }
                // truncating bf16 pack: exact-relative-bias cancels in normalization
                uint2 pk;
                pk.x = (__float_as_uint(p[1]) & 0xffff0000u) | (__float_as_uint(p[0]) >> 16);
                pk.y = (__float_as_uint(p[3]) & 0xffff0000u) | (__float_as_uint(p[2]) >> 16);
                *(uint2*)&P[(ntq * 16 + lr) * LDP + mtk * 16 + lq * 4] = pk;
            }
        }

        // O += P @ V : A = P^T rows (m=q), B = V (n=d)
        v8bf vb[4][2];
#pragma unroll
        for (int ntd = 0; ntd < 4; ntd++) {
#pragma unroll
            for (int half = 0; half < 2; half++) {
                int xb = ((half * 4 + lq) ^ (lr & 7)) * 8;
                vb[ntd][half] = *(const v8bf*)&Vs[(ntd * 16 + lr) * 64 + xb];
            }
        }
#pragma unroll
        for (int mtq = 0; mtq < 2; mtq++) {
            v8bf pa0 = *(const v8bf*)&P[(mtq * 16 + lr) * LDP + lq * 8];
            v8bf pa1 = *(const v8bf*)&P[(mtq * 16 + lr) * LDP + 32 + lq * 8];
#pragma unroll
            for (int ntd = 0; ntd < 4; ntd++) {
                Oacc[mtq][ntd] = __builtin_amdgcn_mfma_f32_16x16x32_bf16(pa0, vb[ntd][0], Oacc[mtq][ntd], 0, 0, 0);
                Oacc[mtq][ntd] = __builtin_amdgcn_mfma_f32_16x16x32_bf16(pa1, vb[ntd][1], Oacc[mtq][ntd], 0, 0, 0);
            }
        }
    }

    // reduce row sums across quads (lane lr then holds total for its q)
    float lsumR[2];
#pragma unroll
    for (int ntq = 0; ntq < 2; ntq++) {
        float s = lsum[ntq];
        s += __shfl_xor(s, 16);
        s += __shfl_xor(s, 32);
        lsumR[ntq] = s;
    }
#pragma unroll
    for (int mtq = 0; mtq < 2; mtq++) {
        float inv[4];
#pragma unroll
        for (int r = 0; r < 4; r++)
            inv[r] = 1.0f / __shfl(lsumR[mtq], lq * 4 + r);
        size_t obase = ((size_t)(b * S_LEN + qw + mtq * 16)) * DMODEL + h * DK;
#pragma unroll
        for (int ntd = 0; ntd < 4; ntd++)
#pragma unroll
            for (int r = 0; r < 4; r++)
                O[obase + (size_t)(lq * 4 + r) * DMODEL + ntd * 16 + lr] = f2bf(Oacc[mtq][ntd][r] * inv[r]);
    }
}

extern "C" void kernel_launch(void* const* d_in, const int* in_sizes, int n_in,
                              void* d_out, int out_size, void* d_ws, size_t ws_size,
                              hipStream_t stream) {
    const float* inputs   = (const float*)d_in[0];
    const int*   lengths  = (const int*)d_in[1];
    const float* W_in     = (const float*)d_in[2];
    const float* b_in     = (const float*)d_in[3];
    const float* Wq       = (const float*)d_in[4];
    const float* bq       = (const float*)d_in[5];
    const float* Wk       = (const float*)d_in[6];
    const float* bk       = (const float*)d_in[7];
    const float* Wv       = (const float*)d_in[8];
    const float* bv       = (const float*)d_in[9];
    const float* Wo       = (const float*)d_in[10];
    const float* bo       = (const float*)d_in[11];
    const float* rel_bias = (const float*)d_in[12];
    const float* W1       = (const float*)d_in[13];
    const float* b1       = (const float*)d_in[14];
    const float* W2       = (const float*)d_in[15];
    const float* b2       = (const float*)d_in[16];
    const float* g1       = (const float*)d_in[17];
    const float* be1      = (const float*)d_in[18];
    const float* g2       = (const float*)d_in[19];
    const float* be2      = (const float*)d_in[20];
    const float* gf       = (const float*)d_in[21];
    const float* bef      = (const float*)d_in[22];

    // ---- workspace layout ----
    char* ws = (char*)d_ws;
    float* xbuf = (float*)ws;          ws += (size_t)MROWS * DMODEL * 4;   // residual fp32
    u16* hbuf   = (u16*)ws;            ws += (size_t)MROWS * DMODEL * 2;   // LN output bf16
    u16* aobuf  = (u16*)ws;            ws += (size_t)MROWS * DMODEL * 2;   // attn output bf16
    u16* qbf    = (u16*)ws;                                                // union region (48MB):
    u16* kbf    = qbf + (size_t)MROWS * DMODEL;                            //  q/k/vt bf16 (24MB)
    u16* vtbf   = kbf + (size_t)MROWS * DMODEL;                            //  OR FFN mid (32MB)
    u16* tbuf   = qbf;                 ws += (size_t)MROWS * DMODEL * 4 * 3;
    u16* inbf   = (u16*)ws;            ws += (size_t)MROWS * IN_DIM * 2;   // bf16 inputs
    u16* wt_in  = (u16*)ws;            ws += (size_t)DMODEL * IN_DIM * 2;
    u16 *qkvw[2], *wto[2], *wt1[2], *wt2[2];
    for (int l = 0; l < 2; l++) { qkvw[l] = (u16*)ws; ws += (size_t)3 * DMODEL * DMODEL * 2; }
    for (int l = 0; l < 2; l++) { wto[l] = (u16*)ws; ws += (size_t)DMODEL * DMODEL * 2; }
    for (int l = 0; l < 2; l++) { wt1[l] = (u16*)ws; ws += (size_t)FF_DIM * DMODEL * 2; }
    for (int l = 0; l < 2; l++) { wt2[l] = (u16*)ws; ws += (size_t)DMODEL * FF_DIM * 2; }

    TArgs ta;
    int ti = 0;
    ta.d[ti++] = {W_in, wt_in, IN_DIM, DMODEL};
    for (int l = 0; l < 2; l++) {
        ta.d[ti++] = {Wq + (size_t)l * DMODEL * DMODEL, qkvw[l], DMODEL, DMODEL};
        ta.d[ti++] = {Wk + (size_t)l * DMODEL * DMODEL, qkvw[l] + (size_t)DMODEL * DMODEL, DMODEL, DMODEL};
        ta.d[ti++] = {Wv + (size_t)l * DMODEL * DMODEL, qkvw[l] + (size_t)2 * DMODEL * DMODEL, DMODEL, DMODEL};
        ta.d[ti++] = {Wo + (size_t)l * DMODEL * DMODEL, wto[l], DMODEL, DMODEL};
        ta.d[ti++] = {W1 + (size_t)l * DMODEL * FF_DIM, wt1[l], DMODEL, FF_DIM};
        ta.d[ti++] = {W2 + (size_t)l * FF_DIM * DMODEL, wt2[l], FF_DIM, DMODEL};
    }

    conv_bf16_kernel<<<dim3((MROWS * IN_DIM / 4 + 255) / 256), 256, 0, stream>>>(
        inputs, inbf, MROWS * IN_DIM / 4);
    transpose_conv_kernel<<<dim3(64, 64, 13), dim3(32, 8), 0, stream>>>(ta);

    gemm_in_kernel<<<dim3(DMODEL / 64, MROWS / 128), 256, 0, stream>>>(
        inbf, wt_in, b_in, xbuf, IN_DIM);

    for (int l = 0; l < 2; l++) {
        ln_kernel<true><<<MROWS / 4, 256, 0, stream>>>(xbuf, g1 + l * DMODEL, be1 + l * DMODEL, hbuf);
        gemm_qkv_kernel<<<dim3(3 * DMODEL / 128, MROWS / 128), 256, 0, stream>>>(
            hbuf, qkvw[l], bq + l * DMODEL, bk + l * DMODEL, bv + l * DMODEL,
            qbf, kbf, vtbf, DMODEL);
        fattn_kernel<<<dim3(S_LEN / 128, NHEAD, B_SZ), 256, 0, stream>>>(
            qbf, kbf, vtbf, rel_bias + (size_t)l * NHEAD * 127, lengths, aobuf);
        gemm_res_kernel<<<dim3(DMODEL / 64, MROWS / 128), 256, 0, stream>>>(
            aobuf, wto[l], bo + l * DMODEL, xbuf, DMODEL);
        ln_kernel<true><<<MROWS / 4, 256, 0, stream>>>(xbuf, g2 + l * DMODEL, be2 + l * DMODEL, hbuf);
        gemm_relu_kernel<<<dim3(FF_DIM / 128, MROWS / 256), 256, 0, stream>>>(
            hbuf, wt1[l], b1 + l * FF_DIM, tbuf, FF_DIM, DMODEL);
        gemm_res_kernel<<<dim3(DMODEL / 64, MROWS / 128), 256, 0, stream>>>(
            tbuf, wt2[l], b2 + l * DMODEL, xbuf, FF_DIM);
    }
    ln_kernel<false><<<MROWS / 4, 256, 0, stream>>>(xbuf, gf, bef, d_out);
}

// Round 8
// 465.359 us; speedup vs baseline: 1.0745x; 1.0745x over previous
//
#include <hip/hip_runtime.h>
#include <hip/hip_bf16.h>

typedef unsigned short u16;
typedef unsigned int u32;
typedef __bf16 v8bf __attribute__((ext_vector_type(8)));
typedef float v4f __attribute__((ext_vector_type(4)));

#define B_SZ 8
#define S_LEN 1024
#define IN_DIM 256
#define DMODEL 512
#define NHEAD 8
#define DK 64
#define FF_DIM 2048
#define MROWS (B_SZ * S_LEN)   // 8192
#define QSCALE 0.1803368801111204f   // 0.125 * log2(e)

__device__ __forceinline__ u16 f2bf(float f) {
    unsigned int x = __float_as_uint(f);
    unsigned int r = (x + 0x7fffu + ((x >> 16) & 1u)) >> 16;
    return (u16)r;
}

// async global->LDS DMA, 16B per lane; lds dest is wave-uniform base + lane*16
__device__ __forceinline__ void gl16(const u16* g, u16* l) {
    __builtin_amdgcn_global_load_lds((const __attribute__((address_space(1))) unsigned int*)g,
                                     (__attribute__((address_space(3))) unsigned int*)l, 16, 0, 0);
}

// ---------------- elementwise f32 -> bf16 (inputs matrix) ----------------
__global__ __launch_bounds__(256) void conv_bf16_kernel(const float* __restrict__ in,
                                                        u16* __restrict__ out, int n4) {
    int i = blockIdx.x * 256 + threadIdx.x;
    if (i < n4) {
        float4 v = ((const float4*)in)[i];
        ushort4 o;
        o.x = f2bf(v.x); o.y = f2bf(v.y); o.z = f2bf(v.z); o.w = f2bf(v.w);
        ((ushort4*)out)[i] = o;
    }
}

// ------------- batched transpose+convert: (K,N) f32 -> (N,K) bf16 -------------
struct TDesc { const float* src; u16* dst; int K; int N; };
struct TArgs { TDesc d[13]; };

__global__ void transpose_conv_kernel(TArgs args) {
    TDesc t = args.d[blockIdx.z];
    int k0 = blockIdx.x * 32, n0 = blockIdx.y * 32;
    if (k0 >= t.K || n0 >= t.N) return;
    __shared__ float tile[32][33];
    int tx = threadIdx.x, ty = threadIdx.y;
#pragma unroll
    for (int j = 0; j < 4; j++) {
        int k = k0 + ty + j * 8;
        tile[ty + j * 8][tx] = t.src[(size_t)k * t.N + n0 + tx];
    }
    __syncthreads();
#pragma unroll
    for (int j = 0; j < 4; j++) {
        int n = n0 + ty + j * 8;
        t.dst[(size_t)n * t.K + k0 + tx] = f2bf(tile[tx][ty + j * 8]);
    }
}

// ---------------- LayerNorm: fp32 in -> bf16 (or fp32) out ----------------
template <bool OUT_BF16>
__global__ __launch_bounds__(256) void ln_kernel(const float* __restrict__ x,
                                                 const float* __restrict__ g,
                                                 const float* __restrict__ b,
                                                 void* __restrict__ out) {
    int row = blockIdx.x * 4 + (threadIdx.x >> 6);
    int lane = threadIdx.x & 63;
    const float4* xr = (const float4*)(x + (size_t)row * DMODEL);
    float4 v0 = xr[lane], v1 = xr[lane + 64];
    float s = v0.x + v0.y + v0.z + v0.w + v1.x + v1.y + v1.z + v1.w;
    float sq = v0.x * v0.x + v0.y * v0.y + v0.z * v0.z + v0.w * v0.w +
               v1.x * v1.x + v1.y * v1.y + v1.z * v1.z + v1.w * v1.w;
#pragma unroll
    for (int m = 1; m < 64; m <<= 1) {
        s += __shfl_xor(s, m);
        sq += __shfl_xor(sq, m);
    }
    float mean = s * (1.0f / DMODEL);
    float var = sq * (1.0f / DMODEL) - mean * mean;
    float rstd = rsqrtf(var + 1e-5f);
    const float4* g4 = (const float4*)g;
    const float4* b4 = (const float4*)b;
    float4 ga = g4[lane], gb = g4[lane + 64], ba = b4[lane], bb = b4[lane + 64];
    float4 r0, r1;
    r0.x = (v0.x - mean) * rstd * ga.x + ba.x;
    r0.y = (v0.y - mean) * rstd * ga.y + ba.y;
    r0.z = (v0.z - mean) * rstd * ga.z + ba.z;
    r0.w = (v0.w - mean) * rstd * ga.w + ba.w;
    r1.x = (v1.x - mean) * rstd * gb.x + bb.x;
    r1.y = (v1.y - mean) * rstd * gb.y + bb.y;
    r1.z = (v1.z - mean) * rstd * gb.z + bb.z;
    r1.w = (v1.w - mean) * rstd * gb.w + bb.w;
    if (OUT_BF16) {
        ushort4 o0, o1;
        o0.x = f2bf(r0.x); o0.y = f2bf(r0.y); o0.z = f2bf(r0.z); o0.w = f2bf(r0.w);
        o1.x = f2bf(r1.x); o1.y = f2bf(r1.y); o1.z = f2bf(r1.z); o1.w = f2bf(r1.w);
        ((ushort4*)out)[(size_t)row * 128 + lane] = o0;
        ((ushort4*)out)[(size_t)row * 128 + 64 + lane] = o1;
    } else {
        ((float4*)out)[(size_t)row * 128 + lane] = r0;
        ((float4*)out)[(size_t)row * 128 + 64 + lane] = r1;
    }
}

// ------- shared GEMM core: (MT*32) x (NT*32) tile, BK=64, XOR-swizzled LDS -------
// global_load_lds width-16; swizzle permutes each lane's GLOBAL source col-block so
// LDS[row][cs] = G[row][cs ^ (row&7)] -> conflict-free b128 frag reads, no padding.
template <int MT, int NT>
__device__ __forceinline__ void gemm_core(const u16* __restrict__ A, const u16* __restrict__ Bt,
                                          int K, v4f (&acc)[MT][NT]) {
    constexpr int BM = MT * 32;
    constexpr int BN = NT * 32;
    __shared__ u16 As[BM * 64];
    __shared__ u16 Bs[BN * 64];
    int tid = threadIdx.x;
    int n0 = blockIdx.x * BN, m0 = blockIdx.y * BM;
    int w = tid >> 6, lane = tid & 63;
    int wr = (w >> 1) * (BM / 2), wc = (w & 1) * (BN / 2);
    int lr = lane & 15, lq = lane >> 4;
    int r8 = lane >> 3, cb = lane & 7;
    int scol = (cb ^ r8) * 8;

    v4f zero = {0.f, 0.f, 0.f, 0.f};
#pragma unroll
    for (int i = 0; i < MT; i++)
#pragma unroll
        for (int j = 0; j < NT; j++) acc[i][j] = zero;

    const u16* gA[MT]; u16* lA[MT];
#pragma unroll
    for (int j = 0; j < MT; j++) {
        int row0 = (MT * 8) * w + j * 8;
        gA[j] = A + (size_t)(m0 + row0 + r8) * K + scol;
        lA[j] = As + row0 * 64;
    }
    const u16* gB[NT]; u16* lB[NT];
#pragma unroll
    for (int j = 0; j < NT; j++) {
        int row0 = (NT * 8) * w + j * 8;
        gB[j] = Bt + (size_t)(n0 + row0 + r8) * K + scol;
        lB[j] = Bs + row0 * 64;
    }

    for (int k0 = 0; k0 < K; k0 += 64) {
#pragma unroll
        for (int j = 0; j < MT; j++) gl16(gA[j], lA[j]);
#pragma unroll
        for (int j = 0; j < NT; j++) gl16(gB[j], lB[j]);
        __syncthreads();   // vmcnt drain -> tiles ready
#pragma unroll
        for (int kk = 0; kk < 2; kk++) {
            int xb = ((kk * 4 + lq) ^ (lr & 7)) * 8;
            v8bf af[MT], bfr[NT];
#pragma unroll
            for (int i = 0; i < MT; i++)
                af[i] = *(const v8bf*)&As[(wr + i * 16 + lr) * 64 + xb];
#pragma unroll
            for (int j = 0; j < NT; j++)
                bfr[j] = *(const v8bf*)&Bs[(wc + j * 16 + lr) * 64 + xb];
#pragma unroll
            for (int mt = 0; mt < MT; mt++)
#pragma unroll
                for (int nt = 0; nt < NT; nt++)
                    acc[mt][nt] = __builtin_amdgcn_mfma_f32_16x16x32_bf16(af[mt], bfr[nt], acc[mt][nt], 0, 0, 0);
        }
        __syncthreads();   // frag reads done before next DMA overwrites
#pragma unroll
        for (int j = 0; j < MT; j++) gA[j] += 64;
#pragma unroll
        for (int j = 0; j < NT; j++) gB[j] += 64;
    }
}

// ---- input projection: fp32 out + bias + sinusoid PE (N=512, 128x64) ----
__global__ __launch_bounds__(256) void gemm_in_kernel(const u16* __restrict__ A,
                                                      const u16* __restrict__ Bt,
                                                      const float* __restrict__ bias,
                                                      float* __restrict__ Out, int K) {
    v4f acc[4][2];
    gemm_core<4, 2>(A, Bt, K, acc);
    int tid = threadIdx.x, w = tid >> 6, lane = tid & 63;
    int lr = lane & 15, lq = lane >> 4;
    int wr = (w >> 1) * 64, wc = (w & 1) * 32;
    int n0 = blockIdx.x * 64, m0 = blockIdx.y * 128;
#pragma unroll
    for (int mt = 0; mt < 4; mt++) {
#pragma unroll
        for (int nt = 0; nt < 2; nt++) {
            int col = n0 + wc + nt * 16 + lr;
            float bcol = bias[col];
            float freq = __builtin_amdgcn_exp2f((float)(col & ~1) * (-0.025953277f));
#pragma unroll
            for (int reg = 0; reg < 4; reg++) {
                int row = m0 + wr + mt * 16 + lq * 4 + reg;
                float rev = (float)(row & (S_LEN - 1)) * freq * 0.15915494309189535f;
                float fr = __builtin_amdgcn_fractf(rev);
                float pe = (col & 1) ? __builtin_amdgcn_cosf(fr) : __builtin_amdgcn_sinf(fr);
                Out[(size_t)row * DMODEL + col] = acc[mt][nt][reg] + bcol + pe;
            }
        }
    }
}

// ---- fused QKV projection: N=1536 (128x128); segment block-uniform ----
__global__ __launch_bounds__(256) void gemm_qkv_kernel(const u16* __restrict__ A,
                                                       const u16* __restrict__ Bt,
                                                       const float* __restrict__ bq,
                                                       const float* __restrict__ bk,
                                                       const float* __restrict__ bv,
                                                       u16* __restrict__ Qo,
                                                       u16* __restrict__ Ko,
                                                       u16* __restrict__ Vto, int K) {
    v4f acc[4][4];
    gemm_core<4, 4>(A, Bt, K, acc);
    int tid = threadIdx.x, w = tid >> 6, lane = tid & 63;
    int lr = lane & 15, lq = lane >> 4;
    int wr = (w >> 1) * 64, wc = (w & 1) * 64;
    int n0 = blockIdx.x * 128, m0 = blockIdx.y * 128;
    int seg = n0 >> 9;
#pragma unroll
    for (int mt = 0; mt < 4; mt++) {
#pragma unroll
        for (int nt = 0; nt < 4; nt++) {
            int col = (n0 + wc + nt * 16 + lr) & (DMODEL - 1);
            if (seg == 0) {
                float bcol = bq[col];
#pragma unroll
                for (int reg = 0; reg < 4; reg++) {
                    int row = m0 + wr + mt * 16 + lq * 4 + reg;
                    Qo[(size_t)row * DMODEL + col] = f2bf((acc[mt][nt][reg] + bcol) * QSCALE);
                }
            } else if (seg == 1) {
                float bcol = bk[col];
#pragma unroll
                for (int reg = 0; reg < 4; reg++) {
                    int row = m0 + wr + mt * 16 + lq * 4 + reg;
                    Ko[(size_t)row * DMODEL + col] = f2bf(acc[mt][nt][reg] + bcol);
                }
            } else {
                float bcol = bv[col];
                int row0 = m0 + wr + mt * 16 + lq * 4;
                int bb = row0 >> 10, s0 = row0 & (S_LEN - 1);
                ushort4 o;
                o.x = f2bf(acc[mt][nt][0] + bcol);
                o.y = f2bf(acc[mt][nt][1] + bcol);
                o.z = f2bf(acc[mt][nt][2] + bcol);
                o.w = f2bf(acc[mt][nt][3] + bcol);
                *(ushort4*)(Vto + ((size_t)(bb * DMODEL + col)) * S_LEN + s0) = o;
            }
        }
    }
}

// ---- FFN1: bf16 out + bias + ReLU (N=2048, 128x128 tile) ----
__global__ __launch_bounds__(256) void gemm_relu_kernel(const u16* __restrict__ A,
                                                        const u16* __restrict__ Bt,
                                                        const float* __restrict__ bias,
                                                        u16* __restrict__ Out, int N, int K) {
    v4f acc[4][4];
    gemm_core<4, 4>(A, Bt, K, acc);
    int tid = threadIdx.x, w = tid >> 6, lane = tid & 63;
    int lr = lane & 15, lq = lane >> 4;
    int wr = (w >> 1) * 64, wc = (w & 1) * 64;
    int n0 = blockIdx.x * 128, m0 = blockIdx.y * 128;
#pragma unroll
    for (int mt = 0; mt < 4; mt++) {
#pragma unroll
        for (int nt = 0; nt < 4; nt++) {
            int col = n0 + wc + nt * 16 + lr;
            float bcol = bias[col];
#pragma unroll
            for (int reg = 0; reg < 4; reg++) {
                int row = m0 + wr + mt * 16 + lq * 4 + reg;
                Out[(size_t)row * N + col] = f2bf(fmaxf(acc[mt][nt][reg] + bcol, 0.0f));
            }
        }
    }
}

// ---- O-proj / FFN2: fp32 out + bias + residual in-place (N=512, 128x64) ----
__global__ __launch_bounds__(256) void gemm_res_kernel(const u16* __restrict__ A,
                                                       const u16* __restrict__ Bt,
                                                       const float* __restrict__ bias,
                                                       float* __restrict__ Out, int K) {
    v4f acc[4][2];
    gemm_core<4, 2>(A, Bt, K, acc);
    int tid = threadIdx.x, w = tid >> 6, lane = tid & 63;
    int lr = lane & 15, lq = lane >> 4;
    int wr = (w >> 1) * 64, wc = (w & 1) * 32;
    int n0 = blockIdx.x * 64, m0 = blockIdx.y * 128;
#pragma unroll
    for (int mt = 0; mt < 4; mt++) {
#pragma unroll
        for (int nt = 0; nt < 2; nt++) {
            int col = n0 + wc + nt * 16 + lr;
            float bcol = bias[col];
#pragma unroll
            for (int reg = 0; reg < 4; reg++) {
                int row = m0 + wr + mt * 16 + lq * 4 + reg;
                size_t idx = (size_t)row * DMODEL + col;
                Out[idx] = Out[idx] + acc[mt][nt][reg] + bcol;
            }
        }
    }
}

// ---------------- MFMA flash attention v6: double-buffered DMA prefetch ----------------
// S^T operand-swap; fixed softmax max; K/V staged by global_load_lds into 2 buffers —
// one barrier per 64-key chunk, chunk i+1 DMA issued before computing chunk i.
#define LDP 68
__global__ __launch_bounds__(256) void fattn_kernel(const u16* __restrict__ Qg,
                                                    const u16* __restrict__ Kg,
                                                    const u16* __restrict__ Vtg,
                                                    const float* __restrict__ rb,
                                                    const int* __restrict__ lengths,
                                                    u16* __restrict__ O) {
    int qt = blockIdx.x, h = blockIdx.y, b = blockIdx.z;
    int tid = threadIdx.x, w = tid >> 6, lane = tid & 63;
    int lr = lane & 15, lq = lane >> 4;
    __shared__ u16 Ks[2][64 * 64];
    __shared__ u16 Vs[2][64 * 64];
    __shared__ u16 Pw[4][32 * LDP];
    __shared__ float rbs[128];
    int len = lengths[b];
    if (tid < 127) rbs[tid] = rb[h * 127 + tid] * 1.4426950408889634f;  // fold log2(e)

    int qw = qt * 128 + w * 32;   // wave's 32 q rows
    v8bf qa[2][2];                // B-operand: rows q = qw + ntq*16 + lr
#pragma unroll
    for (int ntq = 0; ntq < 2; ntq++) {
        size_t qrow = ((size_t)(b * S_LEN + qw + ntq * 16 + lr)) * DMODEL + h * DK;
        qa[ntq][0] = *(const v8bf*)(Qg + qrow + lq * 8);
        qa[ntq][1] = *(const v8bf*)(Qg + qrow + 32 + lq * 8);
    }

    v4f zero = {0.f, 0.f, 0.f, 0.f};
    v4f Oacc[2][4];
#pragma unroll
    for (int mt = 0; mt < 2; mt++)
#pragma unroll
        for (int nt = 0; nt < 4; nt++) Oacc[mt][nt] = zero;
    float lsum[2] = {0.f, 0.f};

    const u16* Kbase = Kg + ((size_t)b * S_LEN) * DMODEL + h * DK;
    const u16* Vbase = Vtg + ((size_t)(b * DMODEL + h * DK)) * S_LEN;
    u16* P = Pw[w];
    int r8 = lane >> 3, cb = lane & 7;
    int swz = (cb ^ r8) * 8;

    // prologue: DMA chunk 0 into buffer 0
#pragma unroll
    for (int j = 0; j < 2; j++) {
        int row0 = w * 16 + j * 8;
        gl16(Kbase + (size_t)(row0 + r8) * DMODEL + swz, Ks[0] + row0 * 64);
        gl16(Vbase + (size_t)(row0 + r8) * S_LEN + swz, Vs[0] + row0 * 64);
    }

    int pb = 0;
    for (int kb0 = 0; kb0 < len; kb0 += 64, pb ^= 1) {
        __syncthreads();   // vmcnt drain: buf[pb] ready; prev compute's reads of buf[pb^1] done

        int nxt = kb0 + 64;
        if (nxt < len) {   // prefetch chunk i+1 into the other buffer (uniform branch)
#pragma unroll
            for (int j = 0; j < 2; j++) {
                int row0 = w * 16 + j * 8;
                gl16(Kbase + (size_t)(nxt + row0 + r8) * DMODEL + swz, Ks[pb ^ 1] + row0 * 64);
                gl16(Vbase + (size_t)(row0 + r8) * S_LEN + nxt + swz, Vs[pb ^ 1] + row0 * 64);
            }
        }
        const u16* Ksc = Ks[pb];
        const u16* Vsc = Vs[pb];

        // A-operand K fragments (swizzled cols): key rows, d cols
        v8bf kf[4][2];
#pragma unroll
        for (int mtk = 0; mtk < 4; mtk++) {
#pragma unroll
            for (int half = 0; half < 2; half++) {
                int xb = ((half * 4 + lq) ^ (lr & 7)) * 8;
                kf[mtk][half] = *(const v8bf*)&Ksc[(mtk * 16 + lr) * 64 + xb];
            }
        }

        // S^T = K @ Q^T : lane holds key = kb0+mtk*16+lq*4+r, q = qw+ntq*16+lr
        v4f S[4][2];
#pragma unroll
        for (int mtk = 0; mtk < 4; mtk++)
#pragma unroll
            for (int ntq = 0; ntq < 2; ntq++) {
                v4f s = __builtin_amdgcn_mfma_f32_16x16x32_bf16(kf[mtk][0], qa[ntq][0], zero, 0, 0, 0);
                S[mtk][ntq] = __builtin_amdgcn_mfma_f32_16x16x32_bf16(kf[mtk][1], qa[ntq][1], s, 0, 0, 0);
            }

        bool edge = (kb0 + 64 > len);
        int dmin = qw - (kb0 + 63), dmax = qw + 31 - kb0;
        bool perel = !(dmax <= -63 || dmin >= 63);
        float bconst = (dmax <= -63) ? rbs[0] : rbs[126];
#pragma unroll
        for (int mtk = 0; mtk < 4; mtk++) {
#pragma unroll
            for (int ntq = 0; ntq < 2; ntq++) {
                int q = qw + ntq * 16 + lr;
                float p[4];
#pragma unroll
                for (int r = 0; r < 4; r++) {
                    int key = kb0 + mtk * 16 + lq * 4 + r;
                    float s = S[mtk][ntq][r];
                    if (perel) {
                        int d = q - key;
                        d = d < -63 ? -63 : (d > 63 ? 63 : d);
                        s += rbs[d + 63];
                    } else {
                        s += bconst;
                    }
                    float pv = __builtin_amdgcn_exp2f(s);
                    if (edge && key >= len) pv = 0.f;
                    lsum[ntq] += pv;
                    p[r] = pv;
                }
                // truncating bf16 pack: relative bias cancels in normalization
                uint2 pk;
                pk.x = (__float_as_uint(p[1]) & 0xffff0000u) | (__float_as_uint(p[0]) >> 16);
                pk.y = (__float_as_uint(p[3]) & 0xffff0000u) | (__float_as_uint(p[2]) >> 16);
                *(uint2*)&P[(ntq * 16 + lr) * LDP + mtk * 16 + lq * 4] = pk;
            }
        }

        // O += P @ V : A = P^T rows (m=q), B = V (n=d)
        v8bf vb[4][2];
#pragma unroll
        for (int ntd = 0; ntd < 4; ntd++) {
#pragma unroll
            for (int half = 0; half < 2; half++) {
                int xb = ((half * 4 + lq) ^ (lr & 7)) * 8;
                vb[ntd][half] = *(const v8bf*)&Vsc[(ntd * 16 + lr) * 64 + xb];
            }
        }
#pragma unroll
        for (int mtq = 0; mtq < 2; mtq++) {
            v8bf pa0 = *(const v8bf*)&P[(mtq * 16 + lr) * LDP + lq * 8];
            v8bf pa1 = *(const v8bf*)&P[(mtq * 16 + lr) * LDP + 32 + lq * 8];
#pragma unroll
            for (int ntd = 0; ntd < 4; ntd++) {
                Oacc[mtq][ntd] = __builtin_amdgcn_mfma_f32_16x16x32_bf16(pa0, vb[ntd][0], Oacc[mtq][ntd], 0, 0, 0);
                Oacc[mtq][ntd] = __builtin_amdgcn_mfma_f32_16x16x32_bf16(pa1, vb[ntd][1], Oacc[mtq][ntd], 0, 0, 0);
            }
        }
    }

    // reduce row sums across quads (lane lr then holds total for its q)
    float lsumR[2];
#pragma unroll
    for (int ntq = 0; ntq < 2; ntq++) {
        float s = lsum[ntq];
        s += __shfl_xor(s, 16);
        s += __shfl_xor(s, 32);
        lsumR[ntq] = s;
    }
#pragma unroll
    for (int mtq = 0; mtq < 2; mtq++) {
        float inv[4];
#pragma unroll
        for (int r = 0; r < 4; r++)
            inv[r] = 1.0f / __shfl(lsumR[mtq], lq * 4 + r);
        size_t obase = ((size_t)(b * S_LEN + qw + mtq * 16)) * DMODEL + h * DK;
#pragma unroll
        for (int ntd = 0; ntd < 4; ntd++)
#pragma unroll
            for (int r = 0; r < 4; r++)
                O[obase + (size_t)(lq * 4 + r) * DMODEL + ntd * 16 + lr] = f2bf(Oacc[mtq][ntd][r] * inv[r]);
    }
}

extern "C" void kernel_launch(void* const* d_in, const int* in_sizes, int n_in,
                              void* d_out, int out_size, void* d_ws, size_t ws_size,
                              hipStream_t stream) {
    const float* inputs   = (const float*)d_in[0];
    const int*   lengths  = (const int*)d_in[1];
    const float* W_in     = (const float*)d_in[2];
    const float* b_in     = (const float*)d_in[3];
    const float* Wq       = (const float*)d_in[4];
    const float* bq       = (const float*)d_in[5];
    const float* Wk       = (const float*)d_in[6];
    const float* bk       = (const float*)d_in[7];
    const float* Wv       = (const float*)d_in[8];
    const float* bv       = (const float*)d_in[9];
    const float* Wo       = (const float*)d_in[10];
    const float* bo       = (const float*)d_in[11];
    const float* rel_bias = (const float*)d_in[12];
    const float* W1       = (const float*)d_in[13];
    const float* b1       = (const float*)d_in[14];
    const float* W2       = (const float*)d_in[15];
    const float* b2       = (const float*)d_in[16];
    const float* g1       = (const float*)d_in[17];
    const float* be1      = (const float*)d_in[18];
    const float* g2       = (const float*)d_in[19];
    const float* be2      = (const float*)d_in[20];
    const float* gf       = (const float*)d_in[21];
    const float* bef      = (const float*)d_in[22];

    // ---- workspace layout ----
    char* ws = (char*)d_ws;
    float* xbuf = (float*)ws;          ws += (size_t)MROWS * DMODEL * 4;   // residual fp32
    u16* hbuf   = (u16*)ws;            ws += (size_t)MROWS * DMODEL * 2;   // LN output bf16
    u16* aobuf  = (u16*)ws;            ws += (size_t)MROWS * DMODEL * 2;   // attn output bf16
    u16* qbf    = (u16*)ws;                                                // union region (48MB):
    u16* kbf    = qbf + (size_t)MROWS * DMODEL;                            //  q/k/vt bf16 (24MB)
    u16* vtbf   = kbf + (size_t)MROWS * DMODEL;                            //  OR FFN mid (32MB)
    u16* tbuf   = qbf;                 ws += (size_t)MROWS * DMODEL * 4 * 3;
    u16* inbf   = (u16*)ws;            ws += (size_t)MROWS * IN_DIM * 2;   // bf16 inputs
    u16* wt_in  = (u16*)ws;            ws += (size_t)DMODEL * IN_DIM * 2;
    u16 *qkvw[2], *wto[2], *wt1[2], *wt2[2];
    for (int l = 0; l < 2; l++) { qkvw[l] = (u16*)ws; ws += (size_t)3 * DMODEL * DMODEL * 2; }
    for (int l = 0; l < 2; l++) { wto[l] = (u16*)ws; ws += (size_t)DMODEL * DMODEL * 2; }
    for (int l = 0; l < 2; l++) { wt1[l] = (u16*)ws; ws += (size_t)FF_DIM * DMODEL * 2; }
    for (int l = 0; l < 2; l++) { wt2[l] = (u16*)ws; ws += (size_t)DMODEL * FF_DIM * 2; }

    TArgs ta;
    int ti = 0;
    ta.d[ti++] = {W_in, wt_in, IN_DIM, DMODEL};
    for (int l = 0; l < 2; l++) {
        ta.d[ti++] = {Wq + (size_t)l * DMODEL * DMODEL, qkvw[l], DMODEL, DMODEL};
        ta.d[ti++] = {Wk + (size_t)l * DMODEL * DMODEL, qkvw[l] + (size_t)DMODEL * DMODEL, DMODEL, DMODEL};
        ta.d[ti++] = {Wv + (size_t)l * DMODEL * DMODEL, qkvw[l] + (size_t)2 * DMODEL * DMODEL, DMODEL, DMODEL};
        ta.d[ti++] = {Wo + (size_t)l * DMODEL * DMODEL, wto[l], DMODEL, DMODEL};
        ta.d[ti++] = {W1 + (size_t)l * DMODEL * FF_DIM, wt1[l], DMODEL, FF_DIM};
        ta.d[ti++] = {W2 + (size_t)l * FF_DIM * DMODEL, wt2[l], FF_DIM, DMODEL};
    }

    conv_bf16_kernel<<<dim3((MROWS * IN_DIM / 4 + 255) / 256), 256, 0, stream>>>(
        inputs, inbf, MROWS * IN_DIM / 4);
    transpose_conv_kernel<<<dim3(64, 64, 13), dim3(32, 8), 0, stream>>>(ta);

    gemm_in_kernel<<<dim3(DMODEL / 64, MROWS / 128), 256, 0, stream>>>(
        inbf, wt_in, b_in, xbuf, IN_DIM);

    for (int l = 0; l < 2; l++) {
        ln_kernel<true><<<MROWS / 4, 256, 0, stream>>>(xbuf, g1 + l * DMODEL, be1 + l * DMODEL, hbuf);
        gemm_qkv_kernel<<<dim3(3 * DMODEL / 128, MROWS / 128), 256, 0, stream>>>(
            hbuf, qkvw[l], bq + l * DMODEL, bk + l * DMODEL, bv + l * DMODEL,
            qbf, kbf, vtbf, DMODEL);
        fattn_kernel<<<dim3(S_LEN / 128, NHEAD, B_SZ), 256, 0, stream>>>(
            qbf, kbf, vtbf, rel_bias + (size_t)l * NHEAD * 127, lengths, aobuf);
        gemm_res_kernel<<<dim3(DMODEL / 64, MROWS / 128), 256, 0, stream>>>(
            aobuf, wto[l], bo + l * DMODEL, xbuf, DMODEL);
        ln_kernel<true><<<MROWS / 4, 256, 0, stream>>>(xbuf, g2 + l * DMODEL, be2 + l * DMODEL, hbuf);
        gemm_relu_kernel<<<dim3(FF_DIM / 128, MROWS / 128), 256, 0, stream>>>(
            hbuf, wt1[l], b1 + l * FF_DIM, tbuf, FF_DIM, DMODEL);
        gemm_res_kernel<<<dim3(DMODEL / 64, MROWS / 128), 256, 0, stream>>>(
            tbuf, wt2[l], b2 + l * DMODEL, xbuf, FF_DIM);
    }
    ln_kernel<false><<<MROWS / 4, 256, 0, stream>>>(xbuf, gf, bef, d_out);
}